// Round 8
// baseline (209.928 us; speedup 1.0000x reference)
//
#include <hip/hip_runtime.h>
#include <hip/hip_bf16.h>
#include <stdint.h>

// QuantizedLinearFSDP: out[m][n] = sum_k x[m][k] * W[n][k] + bias[n]
//   W[n][g*128+s] = codebooks[n][g][codes[n][g][s]]
// M=2048, N=4096, K=4096, G=32, S=128, B=16.
//
// R7 bug: single-phase k-reduction wrote 4 waves x 16KB into a 32KB overlay
// (overlap + OOB). R8 = R7's pipelined K-loop (B LDS double-buffer, one
// barrier/iter, A frags direct global->VGPR) + the R5-verified TWO-PHASE
// k-pair reduction (2 waves x 16KB per phase).

#define M_DIM 2048
#define N_DIM 4096
#define K_DIM 4096

typedef __attribute__((ext_vector_type(4))) int i32x4;

__device__ __forceinline__ void async_load16(const void* g, void* l) {
    __builtin_amdgcn_global_load_lds(
        (const __attribute__((address_space(1))) uint32_t*)(uintptr_t)g,
        (__attribute__((address_space(3))) uint32_t*)(uint32_t)(uintptr_t)l,
        16, 0, 0);
}

__device__ __forceinline__ uint32_t pack4(int a, int b, int c, int d) {
    return (uint32_t)(a & 255) | ((uint32_t)(b & 255) << 8) |
           ((uint32_t)(c & 255) << 16) | ((uint32_t)(d & 255) << 24);
}

__device__ __forceinline__ int q8(float v, float inv) {
    return (int)rintf(v * inv);   // RNE, |v*inv| <= 127 by construction
}

// ---------------- pre-pass: quantize W and x to i8 + per-row scales -------
// blocks [0, 4096): W row o. blocks [4096, 6144): x row m. (unchanged R5)
__global__ __launch_bounds__(256) void prepass_q8(
    const float* __restrict__ cb,      // [4096][32][16]
    const int* __restrict__ codes,     // [4096][32][128]
    const float* __restrict__ x,       // [2048][4096]
    uint32_t* __restrict__ wq,         // [4096][1024] dwords (i8x4)
    uint32_t* __restrict__ xq,         // [2048][1024] dwords (i8x4)
    float* __restrict__ sw,            // [4096]
    float* __restrict__ sx)            // [2048]
{
    __shared__ float scb[512];
    __shared__ float red[256];
    const int b = blockIdx.x, t = threadIdx.x;
    if (b < N_DIM) {
        const int o = b;
        const float c0 = cb[(size_t)o * 512 + t];
        const float c1 = cb[(size_t)o * 512 + 256 + t];
        scb[t] = c0; scb[t + 256] = c1;
        red[t] = fmaxf(fabsf(c0), fabsf(c1));
        __syncthreads();
        for (int s = 128; s > 0; s >>= 1) {
            if (t < s) red[t] = fmaxf(red[t], red[t + s]);
            __syncthreads();
        }
        const float amax = fmaxf(red[0], 1e-20f);
        const float inv = 127.0f / amax;
        if (t == 0) sw[o] = amax / 127.0f;
        const int* crow = codes + (size_t)o * K_DIM;
        uint32_t* orow = wq + (size_t)o * 1024;
#pragma unroll
        for (int i = 0; i < 4; ++i) {
            const int d = t + i * 256;                 // dword index 0..1023
            const int4 c = *(const int4*)(crow + d * 4);
            const float* g = scb + (d >> 5) * 16;      // group = (4d)>>7
            orow[d] = pack4(q8(g[c.x], inv), q8(g[c.y], inv),
                            q8(g[c.z], inv), q8(g[c.w], inv));
        }
    } else {
        const int m = b - N_DIM;
        const float* row = x + (size_t)m * K_DIM;
        float4 v[4];
        float am = 0.f;
#pragma unroll
        for (int i = 0; i < 4; ++i) {
            v[i] = *(const float4*)(row + (size_t)(t + i * 256) * 4);
            am = fmaxf(am, fmaxf(fmaxf(fabsf(v[i].x), fabsf(v[i].y)),
                                 fmaxf(fabsf(v[i].z), fabsf(v[i].w))));
        }
        red[t] = am;
        __syncthreads();
        for (int s = 128; s > 0; s >>= 1) {
            if (t < s) red[t] = fmaxf(red[t], red[t + s]);
            __syncthreads();
        }
        const float amax = fmaxf(red[0], 1e-20f);
        const float inv = 127.0f / amax;
        if (t == 0) sx[m] = amax / 127.0f;
        uint32_t* orow = xq + (size_t)m * 1024;
#pragma unroll
        for (int i = 0; i < 4; ++i)
            orow[t + i * 256] = pack4(q8(v[i].x, inv), q8(v[i].y, inv),
                                      q8(v[i].z, inv), q8(v[i].w, inv));
    }
}

// ---------------- main GEMM (i8): C = A*B^T scaled + bias ----------------
// 128x128 tile, BK=128, 512 threads = 8 waves (wk=w>>2, wm=((w>>1)&1)*64,
// wn=(w&1)*64). Wave: 64x64 sub-tile, acc 4x4 of mfma_i32_16x16x64_i8 over
// its K-half. A frags direct from global. B in LDS, double-buffered 16KB x2;
// 128B rows = 8 x 16B chunks, slot s of row r holds global chunk s ^ (r&7).
__global__ __launch_bounds__(512, 4) void gemm_i8(
    const unsigned char* __restrict__ A,
    const unsigned char* __restrict__ B,
    const float* __restrict__ sx,
    const float* __restrict__ sw,
    const float* __restrict__ bias,
    float* __restrict__ C)
{
    __shared__ __align__(16) unsigned char smem[32768];
    unsigned char* Bs0 = smem;            // [128][128] i8, buf 0
    unsigned char* Bs1 = smem + 16384;    // buf 1

    const int tid  = threadIdx.x;
    const int w    = tid >> 6;        // wave 0..7
    const int lane = tid & 63;
    const int l15  = lane & 15;
    const int quad = lane >> 4;
    const int m0   = blockIdx.y * 128;
    const int n0   = blockIdx.x * 128;
    const int wk   = w >> 2;          // k-half 0/1
    const int wm   = ((w >> 1) & 1) * 64;
    const int wn   = (w & 1) * 64;

    // B staging: 1024 chunks/iter, 2 per thread.
    // chunk c: row = c>>3, slot = c&7, global k-chunk (c&7)^((c>>3)&7).
    const int srow = tid >> 3;                       // 0..63
    const int sc   = (tid & 7) ^ (srow & 7);         // global k-chunk
    const unsigned char* gB0 = B + (size_t)(n0 +      srow) * K_DIM + sc * 16;
    const unsigned char* gB1 = B + (size_t)(n0 + 64 + srow) * K_DIM + sc * 16;
    const int lb0 = w * 1024;          // wave-uniform LDS offsets in buf
    const int lb1 = 8192 + w * 1024;

    // A direct frags: row = m0+wm+i*16+l15, k-chunk = wk*4+quad.
    const unsigned char* gA = A + (size_t)(m0 + wm + l15) * K_DIM
                                + ((wk << 2) + quad) * 16;

    // B frag read: row = wn+i*16+l15 -> slot = (wk*4+quad)^(l15&7).
    const int fs = (((wk << 2) + quad) ^ (l15 & 7)) * 16;

    i32x4 acc[4][4] = {};

    // prologue: stage iter 0 into buf 0
    async_load16(gB0, Bs0 + lb0);
    async_load16(gB1, Bs0 + lb1);
    __syncthreads();

    for (int it = 0; it < 32; ++it) {
        const int k0 = it * 128;
        const unsigned char* cur = (it & 1) ? Bs1 : Bs0;
        unsigned char*       nxt = (it & 1) ? Bs0 : Bs1;

        // issue next iter's B staging first — latency covered by this
        // iter's compute; the end-of-iter barrier drains it.
        if (it + 1 < 32) {
            async_load16(gB0 + k0 + 128, nxt + lb0);
            async_load16(gB1 + k0 + 128, nxt + lb1);
        }

        i32x4 af[4], bfr[4];
#pragma unroll
        for (int i = 0; i < 4; ++i)
            af[i] = *(const i32x4*)(gA + (size_t)i * 16 * K_DIM + k0);
#pragma unroll
        for (int i = 0; i < 4; ++i)
            bfr[i] = *(const i32x4*)(cur + (wn + i * 16 + l15) * 128 + fs);

#pragma unroll
        for (int mi = 0; mi < 4; ++mi)
#pragma unroll
            for (int ni = 0; ni < 4; ++ni)
                acc[mi][ni] = __builtin_amdgcn_mfma_i32_16x16x64_i8(
                    af[mi], bfr[ni], acc[mi][ni], 0, 0, 0);

        __syncthreads();   // drains next-iter B loads + fences cur reads
    }

    // ---- k-pair reduction, TWO PHASES (32KB per phase, R5-verified) ----
    // Pairing: wave w (wk=0) += wave w+4 (wk=1); same (wm, wn).
    i32x4* red = (i32x4*)smem;   // 2048 i32x4 = 32KB
    // Phase A: writers waves 4,5 -> readers waves 0,1
    if (w == 4 || w == 5) {
        i32x4* dst = red + (w & 1) * 1024;
#pragma unroll
        for (int mi = 0; mi < 4; ++mi)
#pragma unroll
            for (int ni = 0; ni < 4; ++ni)
                dst[(mi * 4 + ni) * 64 + lane] = acc[mi][ni];
    }
    __syncthreads();
    if (w == 0 || w == 1) {
        const i32x4* src = red + (w & 1) * 1024;
#pragma unroll
        for (int mi = 0; mi < 4; ++mi)
#pragma unroll
            for (int ni = 0; ni < 4; ++ni) {
                const i32x4 t = src[(mi * 4 + ni) * 64 + lane];
#pragma unroll
                for (int r = 0; r < 4; ++r) acc[mi][ni][r] += t[r];
            }
    }
    __syncthreads();
    // Phase B: writers waves 6,7 -> readers waves 2,3
    if (w == 6 || w == 7) {
        i32x4* dst = red + (w & 1) * 1024;
#pragma unroll
        for (int mi = 0; mi < 4; ++mi)
#pragma unroll
            for (int ni = 0; ni < 4; ++ni)
                dst[(mi * 4 + ni) * 64 + lane] = acc[mi][ni];
    }
    __syncthreads();
    if (w == 2 || w == 3) {
        const i32x4* src = red + (w & 1) * 1024;
#pragma unroll
        for (int mi = 0; mi < 4; ++mi)
#pragma unroll
            for (int ni = 0; ni < 4; ++ni) {
                const i32x4 t = src[(mi * 4 + ni) * 64 + lane];
#pragma unroll
                for (int r = 0; r < 4; ++r) acc[mi][ni][r] += t[r];
            }
    }

    // ---- epilogue (waves 0..3): C/D col = lane&15, row = quad*4+reg ----
    if (wk == 0) {
        float sxv[4][4], swv[4], bv[4];
#pragma unroll
        for (int mi = 0; mi < 4; ++mi)
#pragma unroll
            for (int r = 0; r < 4; ++r)
                sxv[mi][r] = sx[m0 + wm + mi * 16 + quad * 4 + r];
#pragma unroll
        for (int ni = 0; ni < 4; ++ni) {
            const int col = n0 + wn + ni * 16 + l15;
            swv[ni] = sw[col];
            bv[ni]  = bias[col];
        }
#pragma unroll
        for (int mi = 0; mi < 4; ++mi) {
#pragma unroll
            for (int ni = 0; ni < 4; ++ni) {
                const int col = n0 + wn + ni * 16 + l15;
                float* cp = C + (size_t)(m0 + wm + mi * 16 + quad * 4) * N_DIM + col;
#pragma unroll
                for (int r = 0; r < 4; ++r)
                    cp[(size_t)r * N_DIM] =
                        (float)acc[mi][ni][r] * (sxv[mi][r] * swv[ni]) + bv[ni];
            }
        }
    }
}

// ---------------- fallback (ws too small): naive fp32 ----------------
__global__ __launch_bounds__(256) void naive_kernel(
    const float* __restrict__ x, const float* __restrict__ cb,
    const int* __restrict__ codes, const float* __restrict__ bias,
    float* __restrict__ out)
{
    const size_t idx = (size_t)blockIdx.x * 256 + threadIdx.x;  // m*4096 + n
    const int n = (int)(idx & 4095);
    const int m = (int)(idx >> 12);
    const float* xr = x + (size_t)m * K_DIM;
    float s = bias[n];
    for (int g = 0; g < 32; ++g) {
        const float* cbr = cb + ((size_t)n * 32 + g) * 16;
        const int* cr = codes + ((size_t)n * 32 + g) * 128;
        const float* xg = xr + g * 128;
        for (int ss = 0; ss < 128; ++ss) s += xg[ss] * cbr[cr[ss]];
    }
    out[idx] = s;
}

extern "C" void kernel_launch(void* const* d_in, const int* in_sizes, int n_in,
                              void* d_out, int out_size, void* d_ws, size_t ws_size,
                              hipStream_t stream) {
    const float* x     = (const float*)d_in[0];   // [2,1024,4096] f32
    const float* cb    = (const float*)d_in[1];   // [4096,32,16]  f32
    const int*   codes = (const int*)d_in[2];     // [4096,32,128] i32
    const float* bias  = (const float*)d_in[3];   // [4096]        f32
    float* out = (float*)d_out;                   // [2,1024,4096] f32

    const size_t szW = (size_t)N_DIM * K_DIM;          // 16.78 MB i8
    const size_t szX = (size_t)M_DIM * K_DIM;          // 8.39 MB i8
    const size_t need = szW + szX + (N_DIM + M_DIM) * sizeof(float);

    if (ws_size >= need) {
        unsigned char* Wq = (unsigned char*)d_ws;
        unsigned char* Xq = Wq + szW;
        float* sw = (float*)(Xq + szX);
        float* sx = sw + N_DIM;
        prepass_q8<<<dim3(N_DIM + M_DIM), dim3(256), 0, stream>>>(
            cb, codes, x, (uint32_t*)Wq, (uint32_t*)Xq, sw, sx);
        gemm_i8<<<dim3(N_DIM / 128, M_DIM / 128), dim3(512), 0, stream>>>(
            Xq, Wq, sx, sw, bias, out);
    } else {
        naive_kernel<<<dim3((M_DIM * N_DIM) / 256), dim3(256), 0, stream>>>(x, cb, codes, bias, out);
    }
}